// Round 6
// baseline (404.878 us; speedup 1.0000x reference)
//
#include <hip/hip_runtime.h>

typedef __bf16 bf16;
typedef __bf16 bf16x8 __attribute__((ext_vector_type(8)));
typedef __bf16 bf16x4 __attribute__((ext_vector_type(4)));
typedef float f32x4 __attribute__((ext_vector_type(4)));

#define B_ 4
#define L_ 2048
#define E_ 1024
#define H_ 16
#define D_ 64

// workspace layout (bytes)
#define WS_XB    0UL            /* x bf16 [8192][1024]; reused as obuf after attn */
#define WS_WQKV  16777216UL     /* Wqkv^T bf16 [3072][1024] */
#define WS_WOUT  23068672UL     /* Wout^T bf16 [1024][1024] */
#define WS_Q     25165824UL     /* Q bf16 [B*H][L][D] (pre-scaled by 1/8) */
#define WS_K     41943040UL     /* K bf16 [B*H][L][D] */
#define WS_VT    58720256UL     /* V^T bf16 [B*H][D][L] */
#define WS_COS   75497472UL     /* cos fp32 [L][D] */
#define WS_SIN   76021760UL     /* sin fp32 [L][D] */

__device__ __forceinline__ f32x4 mfma16(bf16x8 a, bf16x8 b, f32x4 c) {
    return __builtin_amdgcn_mfma_f32_16x16x32_bf16(a, b, c, 0, 0, 0);
}

__device__ __forceinline__ void gload_lds16(const bf16* src, bf16* ldsDst) {
    __builtin_amdgcn_global_load_lds((const __attribute__((address_space(1))) void*)src,
                                     (__attribute__((address_space(3))) void*)ldsDst, 16, 0, 0);
}

// ---------------- setup kernels ----------------

__global__ void k_cvt_x(const float* __restrict__ x, bf16* __restrict__ xb) {
    const int i = blockIdx.x * blockDim.x + threadIdx.x;  // each handles 4 elems
    float4 v = reinterpret_cast<const float4*>(x)[i];
    bf16x4 o;
    o[0] = (bf16)v.x; o[1] = (bf16)v.y; o[2] = (bf16)v.z; o[3] = (bf16)v.w;
    reinterpret_cast<bf16x4*>(xb)[i] = o;
}

__global__ void k_cossin(const float* __restrict__ f, float* __restrict__ ct, float* __restrict__ st) {
    const int i = blockIdx.x * blockDim.x + threadIdx.x;
    const float v = f[i];
    ct[i] = cosf(v);
    st[i] = sinf(v);
}

// src [R][C] fp32 -> dst [C][R] bf16
__global__ void k_transpose_cvt(const float* __restrict__ src, bf16* __restrict__ dst, int R, int C) {
    __shared__ float tile[32][33];
    const int tx = threadIdx.x & 31, ty = threadIdx.x >> 5;
    const int r0 = blockIdx.y << 5, c0 = blockIdx.x << 5;
    #pragma unroll
    for (int i = 0; i < 32; i += 8)
        tile[ty + i][tx] = src[(size_t)(r0 + ty + i) * C + c0 + tx];
    __syncthreads();
    #pragma unroll
    for (int i = 0; i < 32; i += 8)
        dst[(size_t)(c0 + ty + i) * R + r0 + tx] = (bf16)tile[tx][ty + i];
}

// ---------------- GEMM core (128x128 tile, BK=32, 4 waves 2x2) ----------------
// A [M][1024] K-major, Bm [N][1024] K-major (i.e. B^T). Swizzle: 16B-group ^= (row>>1)&3.

__device__ __forceinline__ void gemm_mainloop(const bf16* __restrict__ A, const bf16* __restrict__ Bm,
                                              int m0, int n0, int w, int lane,
                                              bf16* As, bf16* Bs, f32x4 (&acc)[4][4]) {
    const int wm = w >> 1, wn = w & 1;
    const int lr = lane & 15, lg = lane >> 4;
    for (int kt = 0; kt < 32; ++kt) {
        __syncthreads();
        #pragma unroll
        for (int i = 0; i < 2; ++i) {
            const int chunk = w + i * 4;                 // 0..7, 1KB each
            const int b = chunk * 1024 + lane * 16;      // LDS byte (linear dest)
            const int row = b >> 6;                      // 64B rows (BK=32 bf16)
            const int kg = ((b >> 4) & 3) ^ ((row >> 1) & 3);
            gload_lds16(A  + (size_t)(m0 + row) * 1024 + kt * 32 + kg * 8, As + chunk * 512);
            gload_lds16(Bm + (size_t)(n0 + row) * 1024 + kt * 32 + kg * 8, Bs + chunk * 512);
        }
        asm volatile("s_waitcnt vmcnt(0)" ::: "memory");
        __syncthreads();
        bf16x8 af[4], bfr[4];
        #pragma unroll
        for (int f = 0; f < 4; ++f) {
            const int ra = wm * 64 + f * 16 + lr;
            af[f]  = *reinterpret_cast<const bf16x8*>(As + ra * 32 + ((lg ^ ((ra >> 1) & 3)) * 8));
            const int rb = wn * 64 + f * 16 + lr;
            bfr[f] = *reinterpret_cast<const bf16x8*>(Bs + rb * 32 + ((lg ^ ((rb >> 1) & 3)) * 8));
        }
        #pragma unroll
        for (int mf = 0; mf < 4; ++mf)
            #pragma unroll
            for (int nf = 0; nf < 4; ++nf)
                acc[mf][nf] = mfma16(af[mf], bfr[nf], acc[mf][nf]);
    }
}

// ---------------- QKV GEMM + bias + RoPE epilogue ----------------

__global__ __launch_bounds__(256, 2)
void k_gemm_qkv(const bf16* __restrict__ A, const bf16* __restrict__ Bm,
                const float* __restrict__ bqkv, const float* __restrict__ cosT,
                const float* __restrict__ sinT, bf16* __restrict__ qbuf,
                bf16* __restrict__ kbuf, bf16* __restrict__ vtbuf) {
    __shared__ __align__(16) bf16 As[128 * 32];
    __shared__ __align__(16) bf16 Bs[128 * 32];
    const int t = threadIdx.x, lane = t & 63, w = t >> 6;
    const int m0 = blockIdx.y * 128, n0 = blockIdx.x * 128;
    f32x4 acc[4][4] = {};
    gemm_mainloop(A, Bm, m0, n0, w, lane, As, Bs, acc);

    const int wm = w >> 1, wn = w & 1;
    const int lr = lane & 15, lg = lane >> 4;
    const int c0 = n0 + wn * 64;           // multiple of 64: one head-chunk per wave
    const int sel = c0 >> 10;              // 0=Q 1=K 2=V
    const int h = (c0 & 1023) >> 6;
    float bias[4];
    #pragma unroll
    for (int nf = 0; nf < 4; ++nf) bias[nf] = bqkv[c0 + nf * 16 + lr];

    if (sel < 2) {
        bf16* dst = (sel == 0) ? qbuf : kbuf;
        const float qs = (sel == 0) ? 0.125f : 1.0f;   // fold 1/sqrt(D) into Q
        #pragma unroll
        for (int mf = 0; mf < 4; ++mf) {
            #pragma unroll
            for (int j = 0; j < 4; ++j) {
                const int r = m0 + wm * 64 + mf * 16 + lg * 4 + j;
                const int bb = r >> 11, l = r & 2047;
                const size_t base = ((size_t)(bb * H_ + h)) * (L_ * D_) + (size_t)l * D_;
                #pragma unroll
                for (int p = 0; p < 2; ++p) {
                    const int d1 = p * 16 + lr;        // 0..31
                    const float x1 = acc[mf][p][j]     + bias[p];
                    const float x2 = acc[mf][p + 2][j] + bias[p + 2];
                    dst[base + d1]      = (bf16)((x1 * cosT[l * 64 + d1]      - x2 * sinT[l * 64 + d1])      * qs);
                    dst[base + d1 + 32] = (bf16)((x2 * cosT[l * 64 + d1 + 32] + x1 * sinT[l * 64 + d1 + 32]) * qs);
                }
            }
        }
    } else {
        #pragma unroll
        for (int mf = 0; mf < 4; ++mf) {
            const int r0 = m0 + wm * 64 + mf * 16 + lg * 4;  // 4 consecutive rows (same b)
            const int bb = r0 >> 11, l0 = r0 & 2047;
            #pragma unroll
            for (int nf = 0; nf < 4; ++nf) {
                const int d = nf * 16 + lr;
                bf16x4 v;
                #pragma unroll
                for (int j = 0; j < 4; ++j) v[j] = (bf16)(acc[mf][nf][j] + bias[nf]);
                *reinterpret_cast<bf16x4*>(vtbuf + ((size_t)(bb * H_ + h) * D_ + d) * L_ + l0) = v;
            }
        }
    }
}

// ---------------- flash attention ----------------
// grid (L/64, B*H); block 256 = 4 waves, each wave owns 16 q-rows.
// Double-buffered K/V staging: issue stage(kt+1) BEFORE compute(kt); the single
// __syncthreads() per iter (implicit vmcnt(0)+lgkmcnt(0)+barrier) then lands
// AFTER compute has covered the load latency, and simultaneously protects
// buffer reuse (stage at iter kt+1 overwrites the buffer read at iter kt).
// Pb is wave-private: no barrier needed between P-write and PV read.

__global__ __launch_bounds__(256, 4)
void k_attn(const bf16* __restrict__ qbuf, const bf16* __restrict__ kbuf,
            const bf16* __restrict__ vtbuf, bf16* __restrict__ obuf) {
    __shared__ __align__(16) bf16 Kt[2][64 * 64];    // [key][d], grp ^= key&7
    __shared__ __align__(16) bf16 Vts[2][64 * 64];   // [d][key], grp ^= d&7
    __shared__ __align__(16) bf16 Pb[4][16 * 64];    // per-wave P [q][kk], grp ^= q&7
    const int t = threadIdx.x, lane = t & 63, w = t >> 6;
    const int lr = lane & 15, lg = lane >> 4;
    const int bh = blockIdx.y;
    const int q0 = blockIdx.x * 64;
    const size_t bh_qk = (size_t)bh * (L_ * D_);
    const size_t bh_vt = (size_t)bh * (D_ * L_);

    // per-lane staging addresses (constant across kt)
    const int chunk0 = w, chunk1 = w + 4;
    const int b0 = chunk0 * 1024 + lane * 16, b1 = chunk1 * 1024 + lane * 16;
    const int row0 = b0 >> 7, row1 = b1 >> 7;        // 128B rows
    const int kg0 = ((b0 >> 4) & 7) ^ (row0 & 7), kg1 = ((b1 >> 4) & 7) ^ (row1 & 7);

    bf16x8 qf0, qf1;  // Q A-frags (k=0..31, 32..63), rows = wave's 16 q
    {
        const bf16* qp = qbuf + bh_qk + (size_t)(q0 + w * 16 + lr) * D_ + lg * 8;
        qf0 = *reinterpret_cast<const bf16x8*>(qp);
        qf1 = *reinterpret_cast<const bf16x8*>(qp + 32);
    }
    float rmax[4], rsum[4];
    #pragma unroll
    for (int j = 0; j < 4; ++j) { rmax[j] = -1e30f; rsum[j] = 0.f; }
    f32x4 oacc[4] = {};

    // prologue: stage tile 0 into buffer 0
    {
        gload_lds16(kbuf  + bh_qk + (size_t)(0 * 64 + row0) * D_ + kg0 * 8, &Kt[0][0]  + chunk0 * 512);
        gload_lds16(vtbuf + bh_vt + (size_t)row0 * L_ + 0 * 64 + kg0 * 8,   &Vts[0][0] + chunk0 * 512);
        gload_lds16(kbuf  + bh_qk + (size_t)(0 * 64 + row1) * D_ + kg1 * 8, &Kt[0][0]  + chunk1 * 512);
        gload_lds16(vtbuf + bh_vt + (size_t)row1 * L_ + 0 * 64 + kg1 * 8,   &Vts[0][0] + chunk1 * 512);
    }
    __syncthreads();

    int cur = 0;
    for (int kt = 0; kt < 32; ++kt) {
        // issue next tile's stage into the other buffer (latency hides under compute)
        if (kt < 31) {
            const int nx = cur ^ 1, kn = kt + 1;
            gload_lds16(kbuf  + bh_qk + (size_t)(kn * 64 + row0) * D_ + kg0 * 8, &Kt[nx][0]  + chunk0 * 512);
            gload_lds16(vtbuf + bh_vt + (size_t)row0 * L_ + kn * 64 + kg0 * 8,   &Vts[nx][0] + chunk0 * 512);
            gload_lds16(kbuf  + bh_qk + (size_t)(kn * 64 + row1) * D_ + kg1 * 8, &Kt[nx][0]  + chunk1 * 512);
            gload_lds16(vtbuf + bh_vt + (size_t)row1 * L_ + kn * 64 + kg1 * 8,   &Vts[nx][0] + chunk1 * 512);
        }

        // S = Q K^T (scale pre-folded into Q)
        f32x4 sacc[4] = {};
        #pragma unroll
        for (int ks = 0; ks < 2; ++ks) {
            const bf16x8 qk = ks ? qf1 : qf0;
            #pragma unroll
            for (int nf = 0; nf < 4; ++nf) {
                const int r = nf * 16 + lr;
                const bf16x8 kf = *reinterpret_cast<const bf16x8*>(
                    &Kt[cur][0] + r * 64 + (((ks * 4 + lg) ^ (r & 7)) * 8));
                sacc[nf] = mfma16(qk, kf, sacc[nf]);
            }
        }
        // online softmax: row r=(lg*4+j) lives in the 16 lanes of this lg-group
        #pragma unroll
        for (int j = 0; j < 4; ++j) {
            float pm = fmaxf(fmaxf(sacc[0][j], sacc[1][j]), fmaxf(sacc[2][j], sacc[3][j]));
            #pragma unroll
            for (int d = 1; d < 16; d <<= 1) pm = fmaxf(pm, __shfl_xor(pm, d));
            const float mnew = fmaxf(rmax[j], pm);
            const float scl = __expf(rmax[j] - mnew);
            rmax[j] = mnew;
            float ps = 0.f;
            #pragma unroll
            for (int nf = 0; nf < 4; ++nf) {
                const float p = __expf(sacc[nf][j] - mnew);
                sacc[nf][j] = p;
                ps += p;
            }
            #pragma unroll
            for (int d = 1; d < 16; d <<= 1) ps += __shfl_xor(ps, d);
            rsum[j] = rsum[j] * scl + ps;
            #pragma unroll
            for (int nf = 0; nf < 4; ++nf) oacc[nf][j] *= scl;
        }
        // write P to wave-private LDS (redistribute C-layout -> A-frag layout);
        // same-wave ds_write -> ds_read: compiler inserts lgkmcnt, no barrier needed
        #pragma unroll
        for (int nf = 0; nf < 4; ++nf) {
            #pragma unroll
            for (int j = 0; j < 4; ++j) {
                const int r = lg * 4 + j;
                const int c = nf * 16 + lr;
                Pb[w][r * 64 + (((c >> 3) ^ (r & 7)) * 8) + (c & 7)] = (bf16)sacc[nf][j];
            }
        }
        // O += P V
        #pragma unroll
        for (int ks = 0; ks < 2; ++ks) {
            const bf16x8 pf = *reinterpret_cast<const bf16x8*>(
                &Pb[w][lr * 64 + (((ks * 4 + lg) ^ (lr & 7)) * 8)]);
            #pragma unroll
            for (int nf = 0; nf < 4; ++nf) {
                const int dr = nf * 16 + lr;
                const bf16x8 vf = *reinterpret_cast<const bf16x8*>(
                    &Vts[cur][0] + dr * 64 + (((ks * 4 + lg) ^ (dr & 7)) * 8));
                oacc[nf] = mfma16(pf, vf, oacc[nf]);
            }
        }
        // drain next-stage loads (latency already covered) + release buffers
        __syncthreads();
        cur ^= 1;
    }
    // epilogue: O /= rowsum, write obuf [B][L][H*D] bf16
    const int bI = bh >> 4, h = bh & 15;
    #pragma unroll
    for (int j = 0; j < 4; ++j) {
        const float inv = 1.0f / rsum[j];
        const int qg = q0 + w * 16 + lg * 4 + j;
        const size_t rowb = ((size_t)bI * L_ + qg) * E_ + h * D_;
        #pragma unroll
        for (int nf = 0; nf < 4; ++nf)
            obuf[rowb + nf * 16 + lr] = (bf16)(oacc[nf][j] * inv);
    }
}

// ---------------- output projection ----------------

__global__ __launch_bounds__(256, 2)
void k_gemm_out(const bf16* __restrict__ A, const bf16* __restrict__ Bm,
                const float* __restrict__ bias, float* __restrict__ out) {
    __shared__ __align__(16) bf16 As[128 * 32];
    __shared__ __align__(16) bf16 Bs[128 * 32];
    const int t = threadIdx.x, lane = t & 63, w = t >> 6;
    const int m0 = blockIdx.y * 128, n0 = blockIdx.x * 128;
    f32x4 acc[4][4] = {};
    gemm_mainloop(A, Bm, m0, n0, w, lane, As, Bs, acc);

    const int wm = w >> 1, wn = w & 1;
    const int lr = lane & 15, lg = lane >> 4;
    #pragma unroll
    for (int nf = 0; nf < 4; ++nf) {
        const int c = n0 + wn * 64 + nf * 16 + lr;
        const float bv = bias[c];
        #pragma unroll
        for (int mf = 0; mf < 4; ++mf) {
            #pragma unroll
            for (int j = 0; j < 4; ++j) {
                const int r = m0 + wm * 64 + mf * 16 + lg * 4 + j;
                out[(size_t)r * E_ + c] = acc[mf][nf][j] + bv;
            }
        }
    }
}

// ---------------- launch ----------------

extern "C" void kernel_launch(void* const* d_in, const int* in_sizes, int n_in,
                              void* d_out, int out_size, void* d_ws, size_t ws_size,
                              hipStream_t stream) {
    const float* x     = (const float*)d_in[0];
    const float* freqs = (const float*)d_in[1];
    const float* Wqkv  = (const float*)d_in[2];
    const float* bqkv  = (const float*)d_in[3];
    const float* Wout  = (const float*)d_in[4];
    const float* bout  = (const float*)d_in[5];
    float* out = (float*)d_out;
    char* ws = (char*)d_ws;

    bf16* xb    = (bf16*)(ws + WS_XB);
    bf16* obuf  = (bf16*)(ws + WS_XB);    // alias: x staging reused for attn output
    bf16* wqkvb = (bf16*)(ws + WS_WQKV);
    bf16* woutb = (bf16*)(ws + WS_WOUT);
    bf16* qbuf  = (bf16*)(ws + WS_Q);
    bf16* kbuf  = (bf16*)(ws + WS_K);
    bf16* vtbuf = (bf16*)(ws + WS_VT);
    float* cosT = (float*)(ws + WS_COS);
    float* sinT = (float*)(ws + WS_SIN);

    k_cvt_x<<<8192, 256, 0, stream>>>(x, xb);                               // 8192*1024 elems /4
    k_cossin<<<512, 256, 0, stream>>>(freqs, cosT, sinT);                   // 2048*64
    k_transpose_cvt<<<dim3(96, 32), 256, 0, stream>>>(Wqkv, wqkvb, 1024, 3072);
    k_transpose_cvt<<<dim3(32, 32), 256, 0, stream>>>(Wout, woutb, 1024, 1024);
    k_gemm_qkv<<<dim3(24, 64), 256, 0, stream>>>(xb, wqkvb, bqkv, cosT, sinT, qbuf, kbuf, vtbuf);
    k_attn<<<dim3(32, 64), 256, 0, stream>>>(qbuf, kbuf, vtbuf, obuf);
    k_gemm_out<<<dim3(8, 64), 256, 0, stream>>>(obuf, woutb, bout, out);
}

// Round 7
// 321.538 us; speedup vs baseline: 1.2592x; 1.2592x over previous
//
#include <hip/hip_runtime.h>

typedef __bf16 bf16;
typedef __bf16 bf16x8 __attribute__((ext_vector_type(8)));
typedef __bf16 bf16x4 __attribute__((ext_vector_type(4)));
typedef float f32x4 __attribute__((ext_vector_type(4)));

#define B_ 4
#define L_ 2048
#define E_ 1024
#define H_ 16
#define D_ 64

// workspace layout (bytes)
#define WS_XB    0UL            /* x bf16 [8192][1024]; reused as obuf after attn */
#define WS_WQKV  16777216UL     /* Wqkv^T bf16 [3072][1024] */
#define WS_WOUT  23068672UL     /* Wout^T bf16 [1024][1024] */
#define WS_Q     25165824UL     /* Q bf16 [B*H][L][D] (pre-scaled by 1/8) */
#define WS_K     41943040UL     /* K bf16 [B*H][L][D] */
#define WS_VT    58720256UL     /* V^T bf16 [B*H][D][L] */
#define WS_COS   75497472UL     /* cos fp32 [L][D] */
#define WS_SIN   76021760UL     /* sin fp32 [L][D] */

__device__ __forceinline__ f32x4 mfma16(bf16x8 a, bf16x8 b, f32x4 c) {
    return __builtin_amdgcn_mfma_f32_16x16x32_bf16(a, b, c, 0, 0, 0);
}

__device__ __forceinline__ void gload_lds16(const bf16* src, bf16* ldsDst) {
    __builtin_amdgcn_global_load_lds((const __attribute__((address_space(1))) void*)src,
                                     (__attribute__((address_space(3))) void*)ldsDst, 16, 0, 0);
}

__device__ __forceinline__ f32x4 vmax4(f32x4 a, f32x4 b) {
    f32x4 r;
    r[0] = fmaxf(a[0], b[0]); r[1] = fmaxf(a[1], b[1]);
    r[2] = fmaxf(a[2], b[2]); r[3] = fmaxf(a[3], b[3]);
    return r;
}

// ---------------- setup kernels ----------------

__global__ void k_cvt_x(const float* __restrict__ x, bf16* __restrict__ xb) {
    const int i = blockIdx.x * blockDim.x + threadIdx.x;  // each handles 4 elems
    float4 v = reinterpret_cast<const float4*>(x)[i];
    bf16x4 o;
    o[0] = (bf16)v.x; o[1] = (bf16)v.y; o[2] = (bf16)v.z; o[3] = (bf16)v.w;
    reinterpret_cast<bf16x4*>(xb)[i] = o;
}

__global__ void k_cossin(const float* __restrict__ f, float* __restrict__ ct, float* __restrict__ st) {
    const int i = blockIdx.x * blockDim.x + threadIdx.x;
    const float v = f[i];
    ct[i] = cosf(v);
    st[i] = sinf(v);
}

// src [R][C] fp32 -> dst [C][R] bf16
__global__ void k_transpose_cvt(const float* __restrict__ src, bf16* __restrict__ dst, int R, int C) {
    __shared__ float tile[32][33];
    const int tx = threadIdx.x & 31, ty = threadIdx.x >> 5;
    const int r0 = blockIdx.y << 5, c0 = blockIdx.x << 5;
    #pragma unroll
    for (int i = 0; i < 32; i += 8)
        tile[ty + i][tx] = src[(size_t)(r0 + ty + i) * C + c0 + tx];
    __syncthreads();
    #pragma unroll
    for (int i = 0; i < 32; i += 8)
        dst[(size_t)(c0 + ty + i) * R + r0 + tx] = (bf16)tile[tx][ty + i];
}

// ---------------- GEMM core (128x128 tile, BK=32, 4 waves 2x2) ----------------
// A [M][1024] K-major, Bm [N][1024] K-major (i.e. B^T). Swizzle: 16B-group ^= (row>>1)&3.

__device__ __forceinline__ void gemm_mainloop(const bf16* __restrict__ A, const bf16* __restrict__ Bm,
                                              int m0, int n0, int w, int lane,
                                              bf16* As, bf16* Bs, f32x4 (&acc)[4][4]) {
    const int wm = w >> 1, wn = w & 1;
    const int lr = lane & 15, lg = lane >> 4;
    for (int kt = 0; kt < 32; ++kt) {
        __syncthreads();
        #pragma unroll
        for (int i = 0; i < 2; ++i) {
            const int chunk = w + i * 4;                 // 0..7, 1KB each
            const int b = chunk * 1024 + lane * 16;      // LDS byte (linear dest)
            const int row = b >> 6;                      // 64B rows (BK=32 bf16)
            const int kg = ((b >> 4) & 3) ^ ((row >> 1) & 3);
            gload_lds16(A  + (size_t)(m0 + row) * 1024 + kt * 32 + kg * 8, As + chunk * 512);
            gload_lds16(Bm + (size_t)(n0 + row) * 1024 + kt * 32 + kg * 8, Bs + chunk * 512);
        }
        asm volatile("s_waitcnt vmcnt(0)" ::: "memory");
        __syncthreads();
        bf16x8 af[4], bfr[4];
        #pragma unroll
        for (int f = 0; f < 4; ++f) {
            const int ra = wm * 64 + f * 16 + lr;
            af[f]  = *reinterpret_cast<const bf16x8*>(As + ra * 32 + ((lg ^ ((ra >> 1) & 3)) * 8));
            const int rb = wn * 64 + f * 16 + lr;
            bfr[f] = *reinterpret_cast<const bf16x8*>(Bs + rb * 32 + ((lg ^ ((rb >> 1) & 3)) * 8));
        }
        #pragma unroll
        for (int mf = 0; mf < 4; ++mf)
            #pragma unroll
            for (int nf = 0; nf < 4; ++nf)
                acc[mf][nf] = mfma16(af[mf], bfr[nf], acc[mf][nf]);
    }
}

// ---------------- QKV GEMM + bias + RoPE epilogue ----------------

__global__ __launch_bounds__(256, 2)
void k_gemm_qkv(const bf16* __restrict__ A, const bf16* __restrict__ Bm,
                const float* __restrict__ bqkv, const float* __restrict__ cosT,
                const float* __restrict__ sinT, bf16* __restrict__ qbuf,
                bf16* __restrict__ kbuf, bf16* __restrict__ vtbuf) {
    __shared__ __align__(16) bf16 As[128 * 32];
    __shared__ __align__(16) bf16 Bs[128 * 32];
    const int t = threadIdx.x, lane = t & 63, w = t >> 6;
    const int m0 = blockIdx.y * 128, n0 = blockIdx.x * 128;
    f32x4 acc[4][4] = {};
    gemm_mainloop(A, Bm, m0, n0, w, lane, As, Bs, acc);

    const int wm = w >> 1, wn = w & 1;
    const int lr = lane & 15, lg = lane >> 4;
    const int c0 = n0 + wn * 64;           // multiple of 64: one head-chunk per wave
    const int sel = c0 >> 10;              // 0=Q 1=K 2=V
    const int h = (c0 & 1023) >> 6;
    float bias[4];
    #pragma unroll
    for (int nf = 0; nf < 4; ++nf) bias[nf] = bqkv[c0 + nf * 16 + lr];

    if (sel < 2) {
        bf16* dst = (sel == 0) ? qbuf : kbuf;
        const float qs = (sel == 0) ? 0.125f : 1.0f;   // fold 1/sqrt(D) into Q
        #pragma unroll
        for (int mf = 0; mf < 4; ++mf) {
            #pragma unroll
            for (int j = 0; j < 4; ++j) {
                const int r = m0 + wm * 64 + mf * 16 + lg * 4 + j;
                const int bb = r >> 11, l = r & 2047;
                const size_t base = ((size_t)(bb * H_ + h)) * (L_ * D_) + (size_t)l * D_;
                #pragma unroll
                for (int p = 0; p < 2; ++p) {
                    const int d1 = p * 16 + lr;        // 0..31
                    const float x1 = acc[mf][p][j]     + bias[p];
                    const float x2 = acc[mf][p + 2][j] + bias[p + 2];
                    dst[base + d1]      = (bf16)((x1 * cosT[l * 64 + d1]      - x2 * sinT[l * 64 + d1])      * qs);
                    dst[base + d1 + 32] = (bf16)((x2 * cosT[l * 64 + d1 + 32] + x1 * sinT[l * 64 + d1 + 32]) * qs);
                }
            }
        }
    } else {
        #pragma unroll
        for (int mf = 0; mf < 4; ++mf) {
            const int r0 = m0 + wm * 64 + mf * 16 + lg * 4;  // 4 consecutive rows (same b)
            const int bb = r0 >> 11, l0 = r0 & 2047;
            #pragma unroll
            for (int nf = 0; nf < 4; ++nf) {
                const int d = nf * 16 + lr;
                bf16x4 v;
                #pragma unroll
                for (int j = 0; j < 4; ++j) v[j] = (bf16)(acc[mf][nf][j] + bias[nf]);
                *reinterpret_cast<bf16x4*>(vtbuf + ((size_t)(bb * H_ + h) * D_ + d) * L_ + l0) = v;
            }
        }
    }
}

// ---------------- flash attention ----------------
// grid (L/64, B*H); block 256 = 4 waves, each wave owns 16 q-rows.
// SWAPPED operands: S^T = mfma(K,Q) so lane holds 16 P-scores for its OWN
// q-row (q=lr): row-reduce = in-lane tree + 2 shfl_xor (was 32 shfls/iter).
// PV = mfma(V^T,P): O accumulates [d][q=lr] so rescale + 1/rsum are
// lane-local. Defer-max (HK THR=8) skips the O-rescale when max growth <= 8.

__global__ __launch_bounds__(256, 4)
void k_attn(const bf16* __restrict__ qbuf, const bf16* __restrict__ kbuf,
            const bf16* __restrict__ vtbuf, bf16* __restrict__ obuf) {
    __shared__ __align__(16) bf16 Kt[2][64 * 64];    // [key][d], grp ^= key&7
    __shared__ __align__(16) bf16 Vts[2][64 * 64];   // [d][key], grp ^= d&7
    __shared__ __align__(16) bf16 Pb[4][16 * 64];    // per-wave P [q][key], grp ^= q&7
    const int t = threadIdx.x, lane = t & 63, w = t >> 6;
    const int lr = lane & 15, lg = lane >> 4;
    const int bh = blockIdx.y;
    const int q0 = blockIdx.x * 64;
    const size_t bh_qk = (size_t)bh * (L_ * D_);
    const size_t bh_vt = (size_t)bh * (D_ * L_);

    // per-lane staging addresses (constant across kt)
    const int chunk0 = w, chunk1 = w + 4;
    const int b0 = chunk0 * 1024 + lane * 16, b1 = chunk1 * 1024 + lane * 16;
    const int row0 = b0 >> 7, row1 = b1 >> 7;        // 128B rows
    const int kg0 = ((b0 >> 4) & 7) ^ (row0 & 7), kg1 = ((b1 >> 4) & 7) ^ (row1 & 7);

    bf16x8 qf0, qf1;  // Q frags (d=0..31, 32..63) for rows = wave's 16 q
    {
        const bf16* qp = qbuf + bh_qk + (size_t)(q0 + w * 16 + lr) * D_ + lg * 8;
        qf0 = *reinterpret_cast<const bf16x8*>(qp);
        qf1 = *reinterpret_cast<const bf16x8*>(qp + 32);
    }
    float rmax = -1e30f, rsum = 0.f;   // for q = lr (4 redundant copies across lg)
    f32x4 oacc[4] = {};                // O[q=lr][d = nf*16 + lg*4 + j]

    // prologue: stage tile 0 into buffer 0
    {
        gload_lds16(kbuf  + bh_qk + (size_t)(row0) * D_ + kg0 * 8, &Kt[0][0]  + chunk0 * 512);
        gload_lds16(vtbuf + bh_vt + (size_t)row0 * L_ + kg0 * 8,   &Vts[0][0] + chunk0 * 512);
        gload_lds16(kbuf  + bh_qk + (size_t)(row1) * D_ + kg1 * 8, &Kt[0][0]  + chunk1 * 512);
        gload_lds16(vtbuf + bh_vt + (size_t)row1 * L_ + kg1 * 8,   &Vts[0][0] + chunk1 * 512);
    }
    __syncthreads();

    int cur = 0;
    for (int kt = 0; kt < 32; ++kt) {
        // issue next tile's stage into the other buffer (latency hides under compute)
        if (kt < 31) {
            const int nx = cur ^ 1, kn = kt + 1;
            gload_lds16(kbuf  + bh_qk + (size_t)(kn * 64 + row0) * D_ + kg0 * 8, &Kt[nx][0]  + chunk0 * 512);
            gload_lds16(vtbuf + bh_vt + (size_t)row0 * L_ + kn * 64 + kg0 * 8,   &Vts[nx][0] + chunk0 * 512);
            gload_lds16(kbuf  + bh_qk + (size_t)(kn * 64 + row1) * D_ + kg1 * 8, &Kt[nx][0]  + chunk1 * 512);
            gload_lds16(vtbuf + bh_vt + (size_t)row1 * L_ + kn * 64 + kg1 * 8,   &Vts[nx][0] + chunk1 * 512);
        }

        // S^T = K Q^T: lane holds P[key = nf*16 + lg*4 + j][q = lr]
        f32x4 sacc[4] = {};
        #pragma unroll
        for (int ks = 0; ks < 2; ++ks) {
            const bf16x8 qk = ks ? qf1 : qf0;
            #pragma unroll
            for (int nf = 0; nf < 4; ++nf) {
                const int r = nf * 16 + lr;
                const bf16x8 kf = *reinterpret_cast<const bf16x8*>(
                    &Kt[cur][0] + r * 64 + (((ks * 4 + lg) ^ (r & 7)) * 8));
                sacc[nf] = mfma16(kf, qk, sacc[nf]);
            }
        }
        // online softmax for q=lr: in-lane tree over 16 + 2 shuffles
        f32x4 m4 = vmax4(vmax4(sacc[0], sacc[1]), vmax4(sacc[2], sacc[3]));
        float pm = fmaxf(fmaxf(m4[0], m4[1]), fmaxf(m4[2], m4[3]));
        pm = fmaxf(pm, __shfl_xor(pm, 16));
        pm = fmaxf(pm, __shfl_xor(pm, 32));
        if (!__all(pm - rmax <= 8.0f)) {   // defer-max: rescale only on real growth
            const float mnew = fmaxf(rmax, pm);
            const float scl = __expf(rmax - mnew);
            rsum *= scl;
            #pragma unroll
            for (int nf = 0; nf < 4; ++nf)
                #pragma unroll
                for (int j = 0; j < 4; ++j) oacc[nf][j] *= scl;
            rmax = mnew;
        }
        #pragma unroll
        for (int nf = 0; nf < 4; ++nf)
            #pragma unroll
            for (int j = 0; j < 4; ++j)
                sacc[nf][j] = __expf(sacc[nf][j] - rmax);
        f32x4 s4 = (sacc[0] + sacc[1]) + (sacc[2] + sacc[3]);
        float ps = (s4[0] + s4[1]) + (s4[2] + s4[3]);
        ps += __shfl_xor(ps, 16);
        ps += __shfl_xor(ps, 32);
        rsum += ps;
        // write P to wave-private LDS: row q=lr, keys nf*16+lg*4+{0..3} (bf16x4)
        #pragma unroll
        for (int nf = 0; nf < 4; ++nf) {
            bf16x4 p4;
            #pragma unroll
            for (int j = 0; j < 4; ++j) p4[j] = (bf16)sacc[nf][j];
            const int g = nf * 2 + (lg >> 1);
            *reinterpret_cast<bf16x4*>(
                &Pb[w][lr * 64 + ((g ^ (lr & 7)) * 8) + (lg & 1) * 4]) = p4;
        }
        // O^T += V^T P^T  (same-wave ds_write->ds_read: compiler handles lgkmcnt)
        #pragma unroll
        for (int ks = 0; ks < 2; ++ks) {
            const bf16x8 pf = *reinterpret_cast<const bf16x8*>(
                &Pb[w][lr * 64 + (((ks * 4 + lg) ^ (lr & 7)) * 8)]);
            #pragma unroll
            for (int nf = 0; nf < 4; ++nf) {
                const int dr = nf * 16 + lr;
                const bf16x8 vf = *reinterpret_cast<const bf16x8*>(
                    &Vts[cur][0] + dr * 64 + (((ks * 4 + lg) ^ (dr & 7)) * 8));
                oacc[nf] = mfma16(vf, pf, oacc[nf]);
            }
        }
        // drain next-stage loads (latency already covered) + release buffers
        __syncthreads();
        cur ^= 1;
    }
    // epilogue: O /= rowsum; O[q=lr][d = nf*16 + lg*4 + j] -> obuf [B][L][H*D]
    const int bI = bh >> 4, h = bh & 15;
    const float inv = 1.0f / rsum;
    const int qg = q0 + w * 16 + lr;
    const size_t rowb = ((size_t)bI * L_ + qg) * E_ + h * D_;
    #pragma unroll
    for (int nf = 0; nf < 4; ++nf) {
        bf16x4 o4;
        #pragma unroll
        for (int j = 0; j < 4; ++j) o4[j] = (bf16)(oacc[nf][j] * inv);
        *reinterpret_cast<bf16x4*>(obuf + rowb + nf * 16 + lg * 4) = o4;
    }
}

// ---------------- output projection ----------------

__global__ __launch_bounds__(256, 2)
void k_gemm_out(const bf16* __restrict__ A, const bf16* __restrict__ Bm,
                const float* __restrict__ bias, float* __restrict__ out) {
    __shared__ __align__(16) bf16 As[128 * 32];
    __shared__ __align__(16) bf16 Bs[128 * 32];
    const int t = threadIdx.x, lane = t & 63, w = t >> 6;
    const int m0 = blockIdx.y * 128, n0 = blockIdx.x * 128;
    f32x4 acc[4][4] = {};
    gemm_mainloop(A, Bm, m0, n0, w, lane, As, Bs, acc);

    const int wm = w >> 1, wn = w & 1;
    const int lr = lane & 15, lg = lane >> 4;
    #pragma unroll
    for (int nf = 0; nf < 4; ++nf) {
        const int c = n0 + wn * 64 + nf * 16 + lr;
        const float bv = bias[c];
        #pragma unroll
        for (int mf = 0; mf < 4; ++mf) {
            #pragma unroll
            for (int j = 0; j < 4; ++j) {
                const int r = m0 + wm * 64 + mf * 16 + lg * 4 + j;
                out[(size_t)r * E_ + c] = acc[mf][nf][j] + bv;
            }
        }
    }
}

// ---------------- launch ----------------

extern "C" void kernel_launch(void* const* d_in, const int* in_sizes, int n_in,
                              void* d_out, int out_size, void* d_ws, size_t ws_size,
                              hipStream_t stream) {
    const float* x     = (const float*)d_in[0];
    const float* freqs = (const float*)d_in[1];
    const float* Wqkv  = (const float*)d_in[2];
    const float* bqkv  = (const float*)d_in[3];
    const float* Wout  = (const float*)d_in[4];
    const float* bout  = (const float*)d_in[5];
    float* out = (float*)d_out;
    char* ws = (char*)d_ws;

    bf16* xb    = (bf16*)(ws + WS_XB);
    bf16* obuf  = (bf16*)(ws + WS_XB);    // alias: x staging reused for attn output
    bf16* wqkvb = (bf16*)(ws + WS_WQKV);
    bf16* woutb = (bf16*)(ws + WS_WOUT);
    bf16* qbuf  = (bf16*)(ws + WS_Q);
    bf16* kbuf  = (bf16*)(ws + WS_K);
    bf16* vtbuf = (bf16*)(ws + WS_VT);
    float* cosT = (float*)(ws + WS_COS);
    float* sinT = (float*)(ws + WS_SIN);

    k_cvt_x<<<8192, 256, 0, stream>>>(x, xb);                               // 8192*1024 elems /4
    k_cossin<<<512, 256, 0, stream>>>(freqs, cosT, sinT);                   // 2048*64
    k_transpose_cvt<<<dim3(96, 32), 256, 0, stream>>>(Wqkv, wqkvb, 1024, 3072);
    k_transpose_cvt<<<dim3(32, 32), 256, 0, stream>>>(Wout, woutb, 1024, 1024);
    k_gemm_qkv<<<dim3(24, 64), 256, 0, stream>>>(xb, wqkvb, bqkv, cosT, sinT, qbuf, kbuf, vtbuf);
    k_attn<<<dim3(32, 64), 256, 0, stream>>>(qbuf, kbuf, vtbuf, obuf);
    k_gemm_out<<<dim3(8, 64), 256, 0, stream>>>(obuf, woutb, bout, out);
}